// Round 11
// baseline (3224.670 us; speedup 1.0000x reference)
//
#include <hip/hip_runtime.h>
#include <cstdint>
#include <cstddef>

#define BB 8
#define NN 8192
#define SS 2048
#define KNB 32
#define FLAG_MAGIC 0x5AC3F00Du

// Bit-exact squared distance matching numpy: (a-b) per component, squares,
// left-to-right sum, no FMA contraction.
__device__ __forceinline__ float sqdist_exact(float ax, float ay, float az,
                                              float bx, float by, float bz) {
#pragma clang fp contract(off)
    float dx = ax - bx;
    float dy = ay - by;
    float dz = az - bz;
    return (dx * dx + dy * dy) + dz * dz;
}

// DPP wave-64 reduce steps (gfx9 lineage: row_shr + row_bcast legal on CDNA4).
template <int CTRL>
__device__ __forceinline__ float dpp_fmax_step(float x) {
    int t = __builtin_amdgcn_update_dpp(__float_as_int(-1.0f), __float_as_int(x),
                                        CTRL, 0xf, 0xf, false);
    return fmaxf(x, __int_as_float(t));
}
template <int CTRL>
__device__ __forceinline__ int dpp_imin_step(int x) {
    int t = __builtin_amdgcn_update_dpp(0x7fffffff, x, CTRL, 0xf, 0xf, false);
    return min(x, t);
}
#define ROW_SHR1 0x111
#define ROW_SHR2 0x112
#define ROW_SHR4 0x114
#define ROW_SHR8 0x118
#define ROW_BC15 0x142
#define ROW_BC31 0x143

// ---------------------------------------------------------------------------
// Weight transpose prep: w1T[c][64], w2T[j][64], w3T[j][128]
// ---------------------------------------------------------------------------
__global__ void prep_kernel(const float* __restrict__ w1, const float* __restrict__ w2,
                            const float* __restrict__ w3, float* __restrict__ w1T,
                            float* __restrict__ w2T, float* __restrict__ w3T) {
    for (int i = threadIdx.x; i < 192; i += 256) {
        int oc = i / 3, c = i % 3;
        w1T[c * 64 + oc] = w1[i];
    }
    for (int i = threadIdx.x; i < 4096; i += 256) {
        int oc = i >> 6, j = i & 63;
        w2T[j * 64 + oc] = w2[i];
    }
    for (int i = threadIdx.x; i < 8192; i += 256) {
        int oc = i >> 6, j = i & 63;
        w3T[j * 128 + oc] = w3[i];
    }
}

// spread 3-bit value to bit positions 0,3,6
__device__ __forceinline__ int part3(int v) {
    return (v & 1) | ((v & 2) << 2) | ((v & 4) << 4);
}

#define PT_LIST(X) X(0) X(1) X(2) X(3) X(4) X(5) X(6) X(7) \
                   X(8) X(9) X(10) X(11) X(12) X(13) X(14) X(15)

// ---------------------------------------------------------------------------
// FUSED producer-consumer kernel. Blocks 0..7: the verified-best R7 FPS
// (1891us; 8 waves, 16 pts/thread named regs, waves_per_eu(2,2) forced
// no-spill, Morton sort + wave-uniform exact bbox prune, DPP argmax, 8-slot
// key chain, s_load coords). NEW: tid0 release-stores a per-8-center flag
// (agent scope) after ctr[s] stores -> consumers may start.
// Blocks 8..2055: consumers. Block c-8 -> batch b=(c>>8), group g=(c&255),
// centers 8g..8g+7 as 4 independent pairs (2 waves + LDS slice each, R9's
// exact ball-query + 3-layer MLP + maxpool with in-place h1/h2 reuse).
// tid0 spin-waits (s_sleep + acquire load) for the group flag; the magic
// constant can't be faked by the 0xAA ws poison, and re-poisoning resets
// flags between graph replays. HW dispatches ascending blockIdx -> producer
// blocks 0-7 resident from t=0 (consumers starve-wait otherwise = hang;
// accepted risk, revert if it fires). Makespan ~= fps_end + last-group MLP.
// ---------------------------------------------------------------------------
__global__ __attribute__((amdgpu_flat_work_group_size(512, 512),
                          amdgpu_waves_per_eu(2, 2)))
void fused_kernel(const float* __restrict__ xyz_all,
                  float4* __restrict__ wsSorted,
                  float4* __restrict__ wsCtr,
                  float* __restrict__ out0,
                  int* __restrict__ flags,
                  const float* __restrict__ w1T, const float* __restrict__ b1,
                  const float* __restrict__ w2T, const float* __restrict__ b2,
                  const float* __restrict__ w3T, const float* __restrict__ b3,
                  float* __restrict__ out1) {
    // ---- shared memory (sum of both paths; ~71KB, 1 block/CU either way)
    __shared__ int cellCnt[512];
    __shared__ int cellBase[512];
    __shared__ unsigned long long red[2][8];
    __shared__ float relF[4][2 * KNB * 3];  // per pair: [64 rows][3]
    __shared__ float hT[4][64 * 64];        // per pair: [ch][row], h1 then h2

    const int tid = threadIdx.x;

    if (blockIdx.x < BB) {
        // =================== PRODUCER: FPS (R7 config) ===================
        const int b = blockIdx.x;
        const float* xyz = xyz_all + (size_t)b * NN * 3;
        float4* sorted = wsSorted + (size_t)b * NN;
        float4* ctr = wsCtr + (size_t)b * SS;
        float* o0 = out0 + (size_t)b * 3 * SS;
        int* flg = flags + b * 256;

        const int wid = tid >> 6;
        const int lane = tid & 63;

        // --- pass 1: per-Morton-cell counts (16 pts/thread)
        cellCnt[tid] = 0;
        __syncthreads();
        int cellReg[16];
#pragma unroll
        for (int j = 0; j < 16; ++j) {
            int p = tid + j * 512;
            float x = xyz[p * 3 + 0], y = xyz[p * 3 + 1], z = xyz[p * 3 + 2];
            int qx = min(7, (int)(x * 8.0f));
            int qy = min(7, (int)(y * 8.0f));
            int qz = min(7, (int)(z * 8.0f));
            cellReg[j] = part3(qx) | (part3(qy) << 1) | (part3(qz) << 2);
            atomicAdd(&cellCnt[cellReg[j]], 1);
        }
        __syncthreads();
        int myCnt = cellCnt[tid];
        for (int off = 1; off < 512; off <<= 1) {
            int v = (tid >= off) ? cellCnt[tid - off] : 0;
            __syncthreads();
            cellCnt[tid] += v;
            __syncthreads();
        }
        cellBase[tid] = cellCnt[tid] - myCnt;
        __syncthreads();
        // --- pass 2: scatter; slot s at (s&15)*512 + (s>>4) for coalesced read
#pragma unroll
        for (int j = 0; j < 16; ++j) {
            int p = tid + j * 512;
            float x = xyz[p * 3 + 0], y = xyz[p * 3 + 1], z = xyz[p * 3 + 2];
            int pos = atomicAdd(&cellBase[cellReg[j]], 1);
            sorted[(pos & 15) * 512 + (pos >> 4)] =
                make_float4(x, y, z, __int_as_float(p));
        }
        __threadfence();
        __syncthreads();

        // --- load own 16 Morton-contiguous points + lane bbox
        float lox = 1e30f, loy = 1e30f, loz = 1e30f;
        float hix = -1e30f, hiy = -1e30f, hiz = -1e30f;
#define DECL_PT(i)                          \
    float px##i, py##i, pz##i, dist##i;     \
    int od##i;                              \
    {                                       \
        float4 v = sorted[i * 512 + tid];   \
        px##i = v.x; py##i = v.y; pz##i = v.z; \
        od##i = __float_as_int(v.w);        \
        dist##i = 1e10f;                    \
        lox = fminf(lox, v.x); hix = fmaxf(hix, v.x); \
        loy = fminf(loy, v.y); hiy = fmaxf(hiy, v.y); \
        loz = fminf(loz, v.z); hiz = fmaxf(hiz, v.z); \
    }
        PT_LIST(DECL_PT)

        // wave bbox via one-time shfl butterfly
        float wlox = lox, wloy = loy, wloz = loz;
        float whix = hix, whiy = hiy, whiz = hiz;
#pragma unroll
        for (int off = 1; off < 64; off <<= 1) {
            wlox = fminf(wlox, __shfl_xor(wlox, off));
            wloy = fminf(wloy, __shfl_xor(wloy, off));
            wloz = fminf(wloz, __shfl_xor(wloz, off));
            whix = fmaxf(whix, __shfl_xor(whix, off));
            whiy = fmaxf(whiy, __shfl_xor(whiy, off));
            whiz = fmaxf(whiz, __shfl_xor(whiz, off));
        }

        float cx = xyz[0], cy = xyz[1], cz = xyz[2];
        if (tid == 0) {
            o0[0] = cx; o0[SS] = cy; o0[2 * SS] = cz;
            ctr[0] = make_float4(cx, cy, cz, 0.0f);
        }

        unsigned long long waveKey =
            ((unsigned long long)__float_as_uint(1e10f) << 32) | 0xFFFFFFFFull;
        float wave_bv = 1e10f;

        for (int s = 1; s < SS; ++s) {
            const int par = s & 1;
            float ddx = fmaxf(fmaxf(wlox - cx, cx - whix), 0.0f);
            float ddy = fmaxf(fmaxf(wloy - cy, cy - whiy), 0.0f);
            float ddz = fmaxf(fmaxf(wloz - cz, cz - whiz), 0.0f);
            float lb2 = ddx * ddx + ddy * ddy + ddz * ddz;
            if (lb2 * 0.999f < wave_bv) {
                float nbv = -1.0f;
#define UPD_PT(i)                                                        \
    {                                                                    \
        float d = sqdist_exact(px##i, py##i, pz##i, cx, cy, cz);         \
        dist##i = fminf(dist##i, d);                                     \
        nbv = fmaxf(nbv, dist##i);                                       \
    }
                PT_LIST(UPD_PT)
                float m = nbv;
                m = dpp_fmax_step<ROW_SHR1>(m);
                m = dpp_fmax_step<ROW_SHR2>(m);
                m = dpp_fmax_step<ROW_SHR4>(m);
                m = dpp_fmax_step<ROW_SHR8>(m);
                m = dpp_fmax_step<ROW_BC15>(m);
                m = dpp_fmax_step<ROW_BC31>(m);
                float wv = __int_as_float(
                    __builtin_amdgcn_readlane(__float_as_int(m), 63));
                int cand = 0x7fffffff;
#define IDX_PT(i) cand = (dist##i == wv) ? min(cand, od##i) : cand;
                PT_LIST(IDX_PT)
                cand = dpp_imin_step<ROW_SHR1>(cand);
                cand = dpp_imin_step<ROW_SHR2>(cand);
                cand = dpp_imin_step<ROW_SHR4>(cand);
                cand = dpp_imin_step<ROW_SHR8>(cand);
                cand = dpp_imin_step<ROW_BC15>(cand);
                cand = dpp_imin_step<ROW_BC31>(cand);
                int wiw = __builtin_amdgcn_readlane(cand, 63);
                waveKey = ((unsigned long long)__float_as_uint(wv) << 32) |
                          (unsigned)(~(unsigned)wiw);
                wave_bv = wv;
            }
            if (lane == 0) red[par][wid] = waveKey;
            __syncthreads();
            unsigned long long best = red[par][0];
#pragma unroll
            for (int k = 1; k < 8; ++k) {
                unsigned long long o = red[par][k];
                best = (o > best) ? o : best;
            }
            int wi = (int)(~(unsigned)best);
            int wiu = __builtin_amdgcn_readfirstlane(wi);
            cx = xyz[wiu * 3 + 0];  // scalar broadcast load (s_load)
            cy = xyz[wiu * 3 + 1];
            cz = xyz[wiu * 3 + 2];
            if (tid == 0) {
                o0[s] = cx; o0[SS + s] = cy; o0[2 * SS + s] = cz;
                ctr[s] = make_float4(cx, cy, cz, 0.0f);
                if ((s & 7) == 7) {
                    // release: all prior ctr stores visible before flag
                    __hip_atomic_store(&flg[s >> 3], (int)FLAG_MAGIC,
                                       __ATOMIC_RELEASE, __HIP_MEMORY_SCOPE_AGENT);
                }
            }
        }
    } else {
        // =================== CONSUMER: ball query + MLP ===================
        const int c = blockIdx.x - BB;
        const int b = c >> 8;
        const int g = c & 255;
        const int s0 = g << 3;  // 8 centers per block
        const float* xyz = xyz_all + (size_t)b * NN * 3;
        float* o1 = out1;

        // wait for this group's centers (tid0 spins, others park at barrier)
        if (tid == 0) {
            while (__hip_atomic_load(&flags[b * 256 + g], __ATOMIC_ACQUIRE,
                                     __HIP_MEMORY_SCOPE_AGENT) != (int)FLAG_MAGIC) {
                __builtin_amdgcn_s_sleep(32);
            }
        }
        __syncthreads();

        const int p = tid >> 7;        // pair 0..3 (2 waves each)
        const int tl = tid & 127;
        const int cb = __builtin_amdgcn_readfirstlane(tl >> 6);  // wave in pair
        const int l = tid & 63;
        const int sp = s0 + 2 * p;     // pair's base center

        // ---- ball query: wave cb of pair p handles center sp+cb
        {
            float4 cc = wsCtr[(size_t)b * SS + sp + cb];
            float ccx = cc.x, ccy = cc.y, ccz = cc.z;
            const float R2 = (float)(0.2 * 0.2);
            int total = 0;
            float fx = 0.f, fy = 0.f, fz = 0.f;
            bool have = false;
            for (int chunk = 0; chunk < 128 && total < KNB; ++chunk) {
                int pt = chunk * 64 + l;
                float x = xyz[pt * 3 + 0], y = xyz[pt * 3 + 1], z = xyz[pt * 3 + 2];
                float d = sqdist_exact(ccx, ccy, ccz, x, y, z);
                bool hit = (d <= R2);
                unsigned long long mask = __ballot(hit);
                int cnt = __popcll(mask);
                if (cnt) {
                    int pos = total + __popcll(mask & ((1ull << l) - 1ull));
                    float rx = x - ccx, ry = y - ccy, rz = z - ccz;
                    if (hit && pos < KNB) {
                        relF[p][(cb * KNB + pos) * 3 + 0] = rx;
                        relF[p][(cb * KNB + pos) * 3 + 1] = ry;
                        relF[p][(cb * KNB + pos) * 3 + 2] = rz;
                    }
                    if (hit && pos == 0) { fx = rx; fy = ry; fz = rz; have = true; }
                    total += cnt;
                }
            }
            unsigned long long hm = __ballot(have);
            if (total < KNB) {
                int src = __ffsll((long long)hm) - 1;
                float gx = __shfl(fx, src), gy = __shfl(fy, src), gz = __shfl(fz, src);
                if (l >= total && l < KNB) {
                    relF[p][(cb * KNB + l) * 3 + 0] = gx;
                    relF[p][(cb * KNB + l) * 3 + 1] = gy;
                    relF[p][(cb * KNB + l) * 3 + 2] = gz;
                }
            }
        }
        __syncthreads();

        const int r = l;  // rows 0..31 center sp, rows 32..63 center sp+1

        // ---- layer 1: rel(3) -> 64
        {
            float rx = relF[p][r * 3 + 0], ry = relF[p][r * 3 + 1],
                  rz = relF[p][r * 3 + 2];
#pragma unroll
            for (int i = 0; i < 32; ++i) {
                int ch = cb * 32 + i;
                float h = b1[ch];
                h = fmaf(rx, w1T[0 * 64 + ch], h);
                h = fmaf(ry, w1T[1 * 64 + ch], h);
                h = fmaf(rz, w1T[2 * 64 + ch], h);
                hT[p][ch * 64 + r] = fmaxf(h, 0.0f);
            }
        }
        __syncthreads();

        // ---- layer 2: 64 -> 64 (in-place reuse of hT)
        {
            float acc[32];
#pragma unroll
            for (int i = 0; i < 32; ++i) acc[i] = b2[cb * 32 + i];
#pragma unroll 4
            for (int j = 0; j < 64; ++j) {
                float a = hT[p][j * 64 + r];
                const float* wrow = w2T + j * 64 + cb * 32;
#pragma unroll
                for (int i = 0; i < 32; ++i) acc[i] = fmaf(a, wrow[i], acc[i]);
            }
            __syncthreads();  // all h1 reads complete before overwrite
#pragma unroll
            for (int i = 0; i < 32; ++i)
                hT[p][(cb * 32 + i) * 64 + r] = fmaxf(acc[i], 0.0f);
        }
        __syncthreads();

        // ---- layer 3: 64 -> 128, fused relu + maxpool
        {
            float acc[64];
#pragma unroll
            for (int i = 0; i < 64; ++i) acc[i] = b3[cb * 64 + i];
#pragma unroll 2
            for (int j = 0; j < 64; ++j) {
                float a = hT[p][j * 64 + r];
                const float* wrow = w3T + j * 128 + cb * 64;
#pragma unroll
                for (int i = 0; i < 64; ++i) acc[i] = fmaf(a, wrow[i], acc[i]);
            }
#pragma unroll
            for (int i = 0; i < 64; ++i) {
                float v = fmaxf(acc[i], 0.0f);
                v = fmaxf(v, __shfl_xor(v, 1));
                v = fmaxf(v, __shfl_xor(v, 2));
                v = fmaxf(v, __shfl_xor(v, 4));
                v = fmaxf(v, __shfl_xor(v, 8));
                v = fmaxf(v, __shfl_xor(v, 16));
                acc[i] = v;
            }
            if ((l & 31) == 0) {
                int sA = sp + (l >> 5);
                float* op = o1 + ((size_t)b * 128 + cb * 64) * SS + sA;
#pragma unroll
                for (int i = 0; i < 64; ++i) op[(size_t)i * SS] = acc[i];
            }
        }
    }
}

extern "C" void kernel_launch(void* const* d_in, const int* in_sizes, int n_in,
                              void* d_out, int out_size, void* d_ws, size_t ws_size,
                              hipStream_t stream) {
    (void)in_sizes; (void)n_in; (void)out_size; (void)ws_size;
    const float* xyz = (const float*)d_in[0];
    // d_in[1] = features : unused by the reference
    const float* w1 = (const float*)d_in[2];
    const float* b1 = (const float*)d_in[3];
    const float* w2 = (const float*)d_in[4];
    const float* b2 = (const float*)d_in[5];
    const float* w3 = (const float*)d_in[6];
    const float* b3 = (const float*)d_in[7];
    float* out = (float*)d_out;

    // workspace layout
    float4* wsCtr = (float4*)d_ws;              // B*S float4      (256 KB)
    float4* wsSorted = wsCtr + BB * SS;         // B*N float4      (1 MB)
    float* w1T = (float*)(wsSorted + BB * NN);  // 192 f
    float* w2T = w1T + 192;                     // 4096 f
    float* w3T = w2T + 4096;                    // 8192 f
    int* flags = (int*)(w3T + 8192);            // B*256 ints (8 KB)

    prep_kernel<<<1, 256, 0, stream>>>(w1, w2, w3, w1T, w2T, w3T);
    fused_kernel<<<BB + BB * 256, 512, 0, stream>>>(
        xyz, wsSorted, wsCtr, out, flags, w1T, b1, w2T, b2, w3T, b3,
        out + BB * 3 * SS);
}

// Round 12
// 2102.057 us; speedup vs baseline: 1.5341x; 1.5341x over previous
//
#include <hip/hip_runtime.h>
#include <cstdint>
#include <cstddef>

#define BB 8
#define NN 8192
#define SS 2048
#define KNB 32

// Bit-exact squared distance matching numpy: (a-b) per component, squares,
// left-to-right sum, no FMA contraction.
__device__ __forceinline__ float sqdist_exact(float ax, float ay, float az,
                                              float bx, float by, float bz) {
#pragma clang fp contract(off)
    float dx = ax - bx;
    float dy = ay - by;
    float dz = az - bz;
    return (dx * dx + dy * dy) + dz * dz;
}

// DPP wave-64 reduce steps (gfx9 lineage: row_shr + row_bcast legal on CDNA4).
template <int CTRL>
__device__ __forceinline__ float dpp_fmax_step(float x) {
    int t = __builtin_amdgcn_update_dpp(__float_as_int(-1.0f), __float_as_int(x),
                                        CTRL, 0xf, 0xf, false);
    return fmaxf(x, __int_as_float(t));
}
template <int CTRL>
__device__ __forceinline__ int dpp_imin_step(int x) {
    int t = __builtin_amdgcn_update_dpp(0x7fffffff, x, CTRL, 0xf, 0xf, false);
    return min(x, t);
}
#define ROW_SHR1 0x111
#define ROW_SHR2 0x112
#define ROW_SHR4 0x114
#define ROW_SHR8 0x118
#define ROW_BC15 0x142
#define ROW_BC31 0x143

// ---------------------------------------------------------------------------
// Weight transpose prep: w1T[c][64], w2T[j][64], w3T[j][128]
// ---------------------------------------------------------------------------
__global__ void prep_kernel(const float* __restrict__ w1, const float* __restrict__ w2,
                            const float* __restrict__ w3, float* __restrict__ w1T,
                            float* __restrict__ w2T, float* __restrict__ w3T) {
    for (int i = threadIdx.x; i < 192; i += 256) {
        int oc = i / 3, c = i % 3;
        w1T[c * 64 + oc] = w1[i];
    }
    for (int i = threadIdx.x; i < 4096; i += 256) {
        int oc = i >> 6, j = i & 63;
        w2T[j * 64 + oc] = w2[i];
    }
    for (int i = threadIdx.x; i < 8192; i += 256) {
        int oc = i >> 6, j = i & 63;
        w3T[j * 128 + oc] = w3[i];
    }
}

// spread 3-bit value to bit positions 0,3,6
__device__ __forceinline__ int part3(int v) {
    return (v & 1) | ((v & 2) << 2) | ((v & 4) << 4);
}

#define PT_LIST(X) X(0) X(1) X(2) X(3) X(4) X(5) X(6) X(7) \
                   X(8) X(9) X(10) X(11) X(12) X(13) X(14) X(15)

// ---------------------------------------------------------------------------
// FPS — R7 structure (verified best baseline: 1891us) with the serial chain
// stripped of ALL VMEM ops:
//  * xyz staged as three 32KB LDS planes during the sort prologue -> winner
//    coord fetch = 3 independent broadcast ds_read_b32 (~130cyc, no vmcnt,
//    no K$-miss s_load on the chain).
//  * centers banked in a 32KB LDS ctrLds, written to o0/ctr ONCE after the
//    loop -> no global stores in the loop -> the compiler's pre-barrier
//    s_waitcnt drains lgkm only, not vmcnt(0) store-acks.
// LDS total ~135KB (>64KB static verified OK in R10's fused run; only 8
// blocks on 256 CUs, so 1 block/CU is irrelevant). Everything else identical:
// 8 waves, 16 pts/thread named regs, waves_per_eu(2,2) forced no-spill,
// Morton sort + wave-uniform exact bbox prune, DPP argmax, lane0 publishes
// key, 8-slot compare chain, one barrier/iter (parity double-buffer).
// ---------------------------------------------------------------------------
__global__ __attribute__((amdgpu_flat_work_group_size(512, 512),
                          amdgpu_waves_per_eu(2, 2)))
void fps_kernel(const float* __restrict__ xyz_all,
                float4* __restrict__ wsSorted,
                float4* __restrict__ wsCtr,
                float* __restrict__ out0) {
    const int b = blockIdx.x;
    const float* xyz = xyz_all + (size_t)b * NN * 3;
    float4* sorted = wsSorted + (size_t)b * NN;
    float4* ctr = wsCtr + (size_t)b * SS;
    float* o0 = out0 + (size_t)b * 3 * SS;

    __shared__ float xLds[NN];            // 32KB
    __shared__ float yLds[NN];            // 32KB
    __shared__ float zLds[NN];            // 32KB
    __shared__ float4 ctrLds[SS];         // 32KB
    __shared__ int cellCnt[512];
    __shared__ int cellBase[512];
    __shared__ unsigned long long red[2][8];

    const int tid = threadIdx.x;
    const int wid = tid >> 6;
    const int lane = tid & 63;

    // --- pass 1: per-Morton-cell counts (16 pts/thread) + stage xyz in LDS
    cellCnt[tid] = 0;
    __syncthreads();
    int cellReg[16];
#pragma unroll
    for (int j = 0; j < 16; ++j) {
        int p = tid + j * 512;
        float x = xyz[p * 3 + 0], y = xyz[p * 3 + 1], z = xyz[p * 3 + 2];
        xLds[p] = x; yLds[p] = y; zLds[p] = z;
        int qx = min(7, (int)(x * 8.0f));
        int qy = min(7, (int)(y * 8.0f));
        int qz = min(7, (int)(z * 8.0f));
        cellReg[j] = part3(qx) | (part3(qy) << 1) | (part3(qz) << 2);
        atomicAdd(&cellCnt[cellReg[j]], 1);
    }
    __syncthreads();
    int myCnt = cellCnt[tid];
    // inclusive Hillis-Steele scan over 512 cells (thread==cell)
    for (int off = 1; off < 512; off <<= 1) {
        int v = (tid >= off) ? cellCnt[tid - off] : 0;
        __syncthreads();
        cellCnt[tid] += v;
        __syncthreads();
    }
    cellBase[tid] = cellCnt[tid] - myCnt;
    __syncthreads();
    // --- pass 2: scatter to global ws. Slot s stored at (s&15)*512 + (s>>4)
    // so read-back (thread t owns Morton slots 16t..16t+15) is coalesced.
#pragma unroll
    for (int j = 0; j < 16; ++j) {
        int p = tid + j * 512;
        float x = xLds[p], y = yLds[p], z = zLds[p];
        int pos = atomicAdd(&cellBase[cellReg[j]], 1);
        sorted[(pos & 15) * 512 + (pos >> 4)] = make_float4(x, y, z, __int_as_float(p));
    }
    __threadfence();
    __syncthreads();

    // --- load own 16 Morton-contiguous points into named registers + lane bbox
    float lox = 1e30f, loy = 1e30f, loz = 1e30f;
    float hix = -1e30f, hiy = -1e30f, hiz = -1e30f;
#define DECL_PT(i)                          \
    float px##i, py##i, pz##i, dist##i;     \
    int od##i;                              \
    {                                       \
        float4 v = sorted[i * 512 + tid];   \
        px##i = v.x; py##i = v.y; pz##i = v.z; \
        od##i = __float_as_int(v.w);        \
        dist##i = 1e10f;                    \
        lox = fminf(lox, v.x); hix = fmaxf(hix, v.x); \
        loy = fminf(loy, v.y); hiy = fmaxf(hiy, v.y); \
        loz = fminf(loz, v.z); hiz = fmaxf(hiz, v.z); \
    }
    PT_LIST(DECL_PT)

    // wave bbox via one-time shfl butterfly (not on the hot path)
    float wlox = lox, wloy = loy, wloz = loz, whix = hix, whiy = hiy, whiz = hiz;
#pragma unroll
    for (int off = 1; off < 64; off <<= 1) {
        wlox = fminf(wlox, __shfl_xor(wlox, off));
        wloy = fminf(wloy, __shfl_xor(wloy, off));
        wloz = fminf(wloz, __shfl_xor(wloz, off));
        whix = fmaxf(whix, __shfl_xor(whix, off));
        whiy = fmaxf(whiy, __shfl_xor(whiy, off));
        whiz = fmaxf(whiz, __shfl_xor(whiz, off));
    }

    float cx = xLds[0], cy = yLds[0], cz = zLds[0];
    if (tid == 0) ctrLds[0] = make_float4(cx, cy, cz, 0.0f);

    unsigned long long waveKey =
        ((unsigned long long)__float_as_uint(1e10f) << 32) | 0xFFFFFFFFull;
    float wave_bv = 1e10f;  // max min-dist over this wave's 1024 points (cached)

    for (int s = 1; s < SS; ++s) {
        const int par = s & 1;
        // wave-uniform exact prune: if lb >= wave max dist, no dist can change
        float ddx = fmaxf(fmaxf(wlox - cx, cx - whix), 0.0f);
        float ddy = fmaxf(fmaxf(wloy - cy, cy - whiy), 0.0f);
        float ddz = fmaxf(fmaxf(wloz - cz, cz - whiz), 0.0f);
        float lb2 = ddx * ddx + ddy * ddy + ddz * ddz;
        if (lb2 * 0.999f < wave_bv) {
            float nbv = -1.0f;
#define UPD_PT(i)                                                        \
    {                                                                    \
        float d = sqdist_exact(px##i, py##i, pz##i, cx, cy, cz);         \
        dist##i = fminf(dist##i, d);                                     \
        nbv = fmaxf(nbv, dist##i);                                       \
    }
            PT_LIST(UPD_PT)
            // wave max value via DPP (VALU-speed), result in lane 63
            float m = nbv;
            m = dpp_fmax_step<ROW_SHR1>(m);
            m = dpp_fmax_step<ROW_SHR2>(m);
            m = dpp_fmax_step<ROW_SHR4>(m);
            m = dpp_fmax_step<ROW_SHR8>(m);
            m = dpp_fmax_step<ROW_BC15>(m);
            m = dpp_fmax_step<ROW_BC31>(m);
            float wv = __int_as_float(__builtin_amdgcn_readlane(__float_as_int(m), 63));
            // first-orig-index among exact max holders
            int cand = 0x7fffffff;
#define IDX_PT(i) cand = (dist##i == wv) ? min(cand, od##i) : cand;
            PT_LIST(IDX_PT)
            cand = dpp_imin_step<ROW_SHR1>(cand);
            cand = dpp_imin_step<ROW_SHR2>(cand);
            cand = dpp_imin_step<ROW_SHR4>(cand);
            cand = dpp_imin_step<ROW_SHR8>(cand);
            cand = dpp_imin_step<ROW_BC15>(cand);
            cand = dpp_imin_step<ROW_BC31>(cand);
            int wiw = __builtin_amdgcn_readlane(cand, 63);
            waveKey = ((unsigned long long)__float_as_uint(wv) << 32) |
                      (unsigned)(~(unsigned)wiw);
            wave_bv = wv;
        }
        if (lane == 0) red[par][wid] = waveKey;
        __syncthreads();  // no pending global stores -> lgkm-only drain
        unsigned long long best = red[par][0];
#pragma unroll
        for (int k = 1; k < 8; ++k) {
            unsigned long long o = red[par][k];
            best = (o > best) ? o : best;
        }
        int wi = (int)(~(unsigned)best);
        int wiu = __builtin_amdgcn_readfirstlane(wi);
        cx = xLds[wiu];  // 3 independent broadcast ds_read_b32 (latencies overlap)
        cy = yLds[wiu];
        cz = zLds[wiu];
        if (tid == 0) ctrLds[s] = make_float4(cx, cy, cz, 0.0f);
    }

    // --- single coalesced write-out of all centers
    __syncthreads();
    for (int s = tid; s < SS; s += 512) {
        float4 c = ctrLds[s];
        o0[s] = c.x;
        o0[SS + s] = c.y;
        o0[2 * SS + s] = c.z;
        ctr[s] = c;
    }
}

// ---------------------------------------------------------------------------
// Fused ball-query + MLP + maxpool. Block = 128 threads (2 waves), 2 centers.
// LDS halved (R9): h2 reuses h1's buffer in place -> ~17KB -> ~9 blocks/CU.
// ---------------------------------------------------------------------------
__global__ __launch_bounds__(128) void bqmlp_kernel(const float* __restrict__ xyz_all,
                                                    const float4* __restrict__ wsCtr,
                                                    const float* __restrict__ w1T,
                                                    const float* __restrict__ b1,
                                                    const float* __restrict__ w2T,
                                                    const float* __restrict__ b2,
                                                    const float* __restrict__ w3T,
                                                    const float* __restrict__ b3,
                                                    float* __restrict__ out1) {
    const int b = blockIdx.x >> 10;            // 1024 blocks per batch
    const int s0 = (blockIdx.x & 1023) * 2;    // 2 centers per block
    const float* xyz = xyz_all + (size_t)b * NN * 3;

    __shared__ float relF[2 * KNB * 3];  // [64 rows][3]
    __shared__ float hT[64 * 64];        // [ch][row] — holds h1, then h2

    const int tid = threadIdx.x;
    const int cb = __builtin_amdgcn_readfirstlane(tid >> 6);  // wave id (uniform)
    const int l = tid & 63;

    // ---- ball query: wave cb handles center s0+cb
    {
        float4 cc = wsCtr[(size_t)b * SS + s0 + cb];
        float ccx = cc.x, ccy = cc.y, ccz = cc.z;
        const float R2 = (float)(0.2 * 0.2);
        int total = 0;
        float fx = 0.f, fy = 0.f, fz = 0.f;
        bool have = false;
        for (int chunk = 0; chunk < 128 && total < KNB; ++chunk) {
            int p = chunk * 64 + l;
            float x = xyz[p * 3 + 0], y = xyz[p * 3 + 1], z = xyz[p * 3 + 2];
            float d = sqdist_exact(ccx, ccy, ccz, x, y, z);
            bool hit = (d <= R2);
            unsigned long long mask = __ballot(hit);
            int cnt = __popcll(mask);
            if (cnt) {
                int pos = total + __popcll(mask & ((1ull << l) - 1ull));
                float rx = x - ccx, ry = y - ccy, rz = z - ccz;  // single subs: exact
                if (hit && pos < KNB) {
                    relF[(cb * KNB + pos) * 3 + 0] = rx;
                    relF[(cb * KNB + pos) * 3 + 1] = ry;
                    relF[(cb * KNB + pos) * 3 + 2] = rz;
                }
                if (hit && pos == 0) { fx = rx; fy = ry; fz = rz; have = true; }
                total += cnt;
            }
        }
        unsigned long long hm = __ballot(have);
        if (total < KNB) {
            int src = __ffsll((long long)hm) - 1;
            float gx = __shfl(fx, src), gy = __shfl(fy, src), gz = __shfl(fz, src);
            if (l >= total && l < KNB) {
                relF[(cb * KNB + l) * 3 + 0] = gx;
                relF[(cb * KNB + l) * 3 + 1] = gy;
                relF[(cb * KNB + l) * 3 + 2] = gz;
            }
        }
    }
    __syncthreads();

    const int r = l;  // row 0..63: rows 0..31 center s0, rows 32..63 center s0+1

    // ---- layer 1: rel(3) -> 64, thread covers ch block cb*32..+31 for row r
    {
        float rx = relF[r * 3 + 0], ry = relF[r * 3 + 1], rz = relF[r * 3 + 2];
#pragma unroll
        for (int i = 0; i < 32; ++i) {
            int ch = cb * 32 + i;
            float h = b1[ch];
            h = fmaf(rx, w1T[0 * 64 + ch], h);
            h = fmaf(ry, w1T[1 * 64 + ch], h);
            h = fmaf(rz, w1T[2 * 64 + ch], h);
            hT[ch * 64 + r] = fmaxf(h, 0.0f);
        }
    }
    __syncthreads();

    // ---- layer 2: 64 -> 64 (reads h1 from hT; after barrier, h2 overwrites)
    {
        float acc[32];
#pragma unroll
        for (int i = 0; i < 32; ++i) acc[i] = b2[cb * 32 + i];
#pragma unroll 4
        for (int j = 0; j < 64; ++j) {
            float a = hT[j * 64 + r];
            const float* wrow = w2T + j * 64 + cb * 32;
#pragma unroll
            for (int i = 0; i < 32; ++i) acc[i] = fmaf(a, wrow[i], acc[i]);
        }
        __syncthreads();  // all h1 reads complete before overwrite
#pragma unroll
        for (int i = 0; i < 32; ++i) hT[(cb * 32 + i) * 64 + r] = fmaxf(acc[i], 0.0f);
    }
    __syncthreads();

    // ---- layer 3: 64 -> 128, fused relu + maxpool over the 32 rows/center
    {
        float acc[64];
#pragma unroll
        for (int i = 0; i < 64; ++i) acc[i] = b3[cb * 64 + i];
#pragma unroll 2
        for (int j = 0; j < 64; ++j) {
            float a = hT[j * 64 + r];
            const float* wrow = w3T + j * 128 + cb * 64;
#pragma unroll
            for (int i = 0; i < 64; ++i) acc[i] = fmaf(a, wrow[i], acc[i]);
        }
#pragma unroll
        for (int i = 0; i < 64; ++i) {
            float v = fmaxf(acc[i], 0.0f);
            v = fmaxf(v, __shfl_xor(v, 1));
            v = fmaxf(v, __shfl_xor(v, 2));
            v = fmaxf(v, __shfl_xor(v, 4));
            v = fmaxf(v, __shfl_xor(v, 8));
            v = fmaxf(v, __shfl_xor(v, 16));
            acc[i] = v;
        }
        if ((l & 31) == 0) {
            int sA = s0 + (l >> 5);
            float* op = out1 + ((size_t)b * 128 + cb * 64) * SS + sA;
#pragma unroll
            for (int i = 0; i < 64; ++i) op[(size_t)i * SS] = acc[i];
        }
    }
}

extern "C" void kernel_launch(void* const* d_in, const int* in_sizes, int n_in,
                              void* d_out, int out_size, void* d_ws, size_t ws_size,
                              hipStream_t stream) {
    (void)in_sizes; (void)n_in; (void)out_size; (void)ws_size;
    const float* xyz = (const float*)d_in[0];
    // d_in[1] = features : unused by the reference
    const float* w1 = (const float*)d_in[2];
    const float* b1 = (const float*)d_in[3];
    const float* w2 = (const float*)d_in[4];
    const float* b2 = (const float*)d_in[5];
    const float* w3 = (const float*)d_in[6];
    const float* b3 = (const float*)d_in[7];
    float* out = (float*)d_out;

    // workspace layout
    float4* wsCtr = (float4*)d_ws;              // B*S float4      (256 KB)
    float4* wsSorted = wsCtr + BB * SS;         // B*N float4      (1 MB)
    float* w1T = (float*)(wsSorted + BB * NN);  // 192 f
    float* w2T = w1T + 192;                     // 4096 f
    float* w3T = w2T + 4096;                    // 8192 f

    prep_kernel<<<1, 256, 0, stream>>>(w1, w2, w3, w1T, w2T, w3T);
    fps_kernel<<<BB, 512, 0, stream>>>(xyz, wsSorted, wsCtr, out);
    bqmlp_kernel<<<BB * (SS / 2), 128, 0, stream>>>(xyz, wsCtr, w1T, b1, w2T, b2,
                                                    w3T, b3, out + BB * 3 * SS);
}

// Round 13
// 2001.954 us; speedup vs baseline: 1.6108x; 1.0500x over previous
//
#include <hip/hip_runtime.h>
#include <cstdint>
#include <cstddef>

#define BB 8
#define NN 8192
#define SS 2048
#define KNB 32

// Bit-exact squared distance matching numpy: (a-b) per component, squares,
// left-to-right sum, no FMA contraction.
__device__ __forceinline__ float sqdist_exact(float ax, float ay, float az,
                                              float bx, float by, float bz) {
#pragma clang fp contract(off)
    float dx = ax - bx;
    float dy = ay - by;
    float dz = az - bz;
    return (dx * dx + dy * dy) + dz * dz;
}

// DPP wave-64 reduce steps (gfx9 lineage: row_shr + row_bcast legal on CDNA4).
template <int CTRL>
__device__ __forceinline__ float dpp_fmax_step(float x) {
    int t = __builtin_amdgcn_update_dpp(__float_as_int(-1.0f), __float_as_int(x),
                                        CTRL, 0xf, 0xf, false);
    return fmaxf(x, __int_as_float(t));
}
template <int CTRL>
__device__ __forceinline__ int dpp_imin_step(int x) {
    int t = __builtin_amdgcn_update_dpp(0x7fffffff, x, CTRL, 0xf, 0xf, false);
    return min(x, t);
}
// u64 max step via DPP (2 dpp movs + u64 cmp/select, pure VALU). Identity 0
// is safe: keys are always non-negative (dist bits in the high half).
template <int CTRL>
__device__ __forceinline__ unsigned long long dpp_u64max_step(unsigned long long k) {
    int lo = __builtin_amdgcn_update_dpp(0, (int)(unsigned)(k & 0xffffffffu),
                                         CTRL, 0xf, 0xf, false);
    int hi = __builtin_amdgcn_update_dpp(0, (int)(unsigned)(k >> 32),
                                         CTRL, 0xf, 0xf, false);
    unsigned long long o = ((unsigned long long)(unsigned)hi << 32) | (unsigned)lo;
    return (o > k) ? o : k;
}
#define ROW_SHR1 0x111
#define ROW_SHR2 0x112
#define ROW_SHR4 0x114
#define ROW_SHR8 0x118
#define ROW_BC15 0x142
#define ROW_BC31 0x143

// ---------------------------------------------------------------------------
// Weight transpose prep: w1T[c][64], w2T[j][64], w3T[j][128]
// ---------------------------------------------------------------------------
__global__ void prep_kernel(const float* __restrict__ w1, const float* __restrict__ w2,
                            const float* __restrict__ w3, float* __restrict__ w1T,
                            float* __restrict__ w2T, float* __restrict__ w3T) {
    for (int i = threadIdx.x; i < 192; i += 256) {
        int oc = i / 3, c = i % 3;
        w1T[c * 64 + oc] = w1[i];
    }
    for (int i = threadIdx.x; i < 4096; i += 256) {
        int oc = i >> 6, j = i & 63;
        w2T[j * 64 + oc] = w2[i];
    }
    for (int i = threadIdx.x; i < 8192; i += 256) {
        int oc = i >> 6, j = i & 63;
        w3T[j * 128 + oc] = w3[i];
    }
}

// spread 3-bit value to bit positions 0,3,6
__device__ __forceinline__ int part3(int v) {
    return (v & 1) | ((v & 2) << 2) | ((v & 4) << 4);
}

#define PT_LIST(X) X(0) X(1) X(2) X(3) X(4) X(5) X(6) X(7) \
                   X(8) X(9) X(10) X(11) X(12) X(13) X(14) X(15)

// ---------------------------------------------------------------------------
// FPS — R12 structure (verified best: 1778us; all-LDS serial chain, no VMEM
// in the loop) with the cross-wave tail's DS-instruction count cut 12->5 per
// wave: the 8 broadcast key reads + 7-deep u64 compare chain are replaced by
// ONE lane-indexed ds_read_b64 (red[lane&7]) + 3 DPP row_shr u64-max steps
// (pure VALU) + one readlane of the low half (the winning index IS the key's
// low 32 bits — no ballot, no coord slots). The tail was DS-pipe-occupancy
// bound (~96 DS ops/iter through one CU's LDS pipe), not latency bound.
// Everything else identical: 8 waves, 16 pts/thread named regs,
// waves_per_eu(2,2) forced no-spill, Morton sort + wave-uniform exact bbox
// prune, DPP argmax in-wave, xyz in three LDS planes, centers banked in
// ctrLds and written out once, one barrier/iter (parity double-buffer).
// ---------------------------------------------------------------------------
__global__ __attribute__((amdgpu_flat_work_group_size(512, 512),
                          amdgpu_waves_per_eu(2, 2)))
void fps_kernel(const float* __restrict__ xyz_all,
                float4* __restrict__ wsSorted,
                float4* __restrict__ wsCtr,
                float* __restrict__ out0) {
    const int b = blockIdx.x;
    const float* xyz = xyz_all + (size_t)b * NN * 3;
    float4* sorted = wsSorted + (size_t)b * NN;
    float4* ctr = wsCtr + (size_t)b * SS;
    float* o0 = out0 + (size_t)b * 3 * SS;

    __shared__ float xLds[NN];            // 32KB
    __shared__ float yLds[NN];            // 32KB
    __shared__ float zLds[NN];            // 32KB
    __shared__ float4 ctrLds[SS];         // 32KB
    __shared__ int cellCnt[512];
    __shared__ int cellBase[512];
    __shared__ unsigned long long red[2][8];

    const int tid = threadIdx.x;
    const int wid = tid >> 6;
    const int lane = tid & 63;

    // --- pass 1: per-Morton-cell counts (16 pts/thread) + stage xyz in LDS
    cellCnt[tid] = 0;
    __syncthreads();
    int cellReg[16];
#pragma unroll
    for (int j = 0; j < 16; ++j) {
        int p = tid + j * 512;
        float x = xyz[p * 3 + 0], y = xyz[p * 3 + 1], z = xyz[p * 3 + 2];
        xLds[p] = x; yLds[p] = y; zLds[p] = z;
        int qx = min(7, (int)(x * 8.0f));
        int qy = min(7, (int)(y * 8.0f));
        int qz = min(7, (int)(z * 8.0f));
        cellReg[j] = part3(qx) | (part3(qy) << 1) | (part3(qz) << 2);
        atomicAdd(&cellCnt[cellReg[j]], 1);
    }
    __syncthreads();
    int myCnt = cellCnt[tid];
    // inclusive Hillis-Steele scan over 512 cells (thread==cell)
    for (int off = 1; off < 512; off <<= 1) {
        int v = (tid >= off) ? cellCnt[tid - off] : 0;
        __syncthreads();
        cellCnt[tid] += v;
        __syncthreads();
    }
    cellBase[tid] = cellCnt[tid] - myCnt;
    __syncthreads();
    // --- pass 2: scatter to global ws. Slot s stored at (s&15)*512 + (s>>4)
    // so read-back (thread t owns Morton slots 16t..16t+15) is coalesced.
#pragma unroll
    for (int j = 0; j < 16; ++j) {
        int p = tid + j * 512;
        float x = xLds[p], y = yLds[p], z = zLds[p];
        int pos = atomicAdd(&cellBase[cellReg[j]], 1);
        sorted[(pos & 15) * 512 + (pos >> 4)] = make_float4(x, y, z, __int_as_float(p));
    }
    __threadfence();
    __syncthreads();

    // --- load own 16 Morton-contiguous points into named registers + lane bbox
    float lox = 1e30f, loy = 1e30f, loz = 1e30f;
    float hix = -1e30f, hiy = -1e30f, hiz = -1e30f;
#define DECL_PT(i)                          \
    float px##i, py##i, pz##i, dist##i;     \
    int od##i;                              \
    {                                       \
        float4 v = sorted[i * 512 + tid];   \
        px##i = v.x; py##i = v.y; pz##i = v.z; \
        od##i = __float_as_int(v.w);        \
        dist##i = 1e10f;                    \
        lox = fminf(lox, v.x); hix = fmaxf(hix, v.x); \
        loy = fminf(loy, v.y); hiy = fmaxf(hiy, v.y); \
        loz = fminf(loz, v.z); hiz = fmaxf(hiz, v.z); \
    }
    PT_LIST(DECL_PT)

    // wave bbox via one-time shfl butterfly (not on the hot path)
    float wlox = lox, wloy = loy, wloz = loz, whix = hix, whiy = hiy, whiz = hiz;
#pragma unroll
    for (int off = 1; off < 64; off <<= 1) {
        wlox = fminf(wlox, __shfl_xor(wlox, off));
        wloy = fminf(wloy, __shfl_xor(wloy, off));
        wloz = fminf(wloz, __shfl_xor(wloz, off));
        whix = fmaxf(whix, __shfl_xor(whix, off));
        whiy = fmaxf(whiy, __shfl_xor(whiy, off));
        whiz = fmaxf(whiz, __shfl_xor(whiz, off));
    }

    float cx = xLds[0], cy = yLds[0], cz = zLds[0];
    if (tid == 0) ctrLds[0] = make_float4(cx, cy, cz, 0.0f);

    unsigned long long waveKey =
        ((unsigned long long)__float_as_uint(1e10f) << 32) | 0xFFFFFFFFull;
    float wave_bv = 1e10f;  // max min-dist over this wave's 1024 points (cached)

    for (int s = 1; s < SS; ++s) {
        const int par = s & 1;
        // wave-uniform exact prune: if lb >= wave max dist, no dist can change
        float ddx = fmaxf(fmaxf(wlox - cx, cx - whix), 0.0f);
        float ddy = fmaxf(fmaxf(wloy - cy, cy - whiy), 0.0f);
        float ddz = fmaxf(fmaxf(wloz - cz, cz - whiz), 0.0f);
        float lb2 = ddx * ddx + ddy * ddy + ddz * ddz;
        if (lb2 * 0.999f < wave_bv) {
            float nbv = -1.0f;
#define UPD_PT(i)                                                        \
    {                                                                    \
        float d = sqdist_exact(px##i, py##i, pz##i, cx, cy, cz);         \
        dist##i = fminf(dist##i, d);                                     \
        nbv = fmaxf(nbv, dist##i);                                       \
    }
            PT_LIST(UPD_PT)
            // wave max value via DPP (VALU-speed), result in lane 63
            float m = nbv;
            m = dpp_fmax_step<ROW_SHR1>(m);
            m = dpp_fmax_step<ROW_SHR2>(m);
            m = dpp_fmax_step<ROW_SHR4>(m);
            m = dpp_fmax_step<ROW_SHR8>(m);
            m = dpp_fmax_step<ROW_BC15>(m);
            m = dpp_fmax_step<ROW_BC31>(m);
            float wv = __int_as_float(__builtin_amdgcn_readlane(__float_as_int(m), 63));
            // first-orig-index among exact max holders
            int cand = 0x7fffffff;
#define IDX_PT(i) cand = (dist##i == wv) ? min(cand, od##i) : cand;
            PT_LIST(IDX_PT)
            cand = dpp_imin_step<ROW_SHR1>(cand);
            cand = dpp_imin_step<ROW_SHR2>(cand);
            cand = dpp_imin_step<ROW_SHR4>(cand);
            cand = dpp_imin_step<ROW_SHR8>(cand);
            cand = dpp_imin_step<ROW_BC15>(cand);
            cand = dpp_imin_step<ROW_BC31>(cand);
            int wiw = __builtin_amdgcn_readlane(cand, 63);
            waveKey = ((unsigned long long)__float_as_uint(wv) << 32) |
                      (unsigned)(~(unsigned)wiw);
            wave_bv = wv;
        }
        if (lane == 0) red[par][wid] = waveKey;
        __syncthreads();  // lgkm-only drain (no global ops in loop)
        // cross-wave reduce: ONE lane-indexed b64 read + 3 DPP row_shr u64-max
        // steps (lane 7 of each 16-row = max over slots 0..7); the winning
        // index is the low half of the max key -> one readlane, no ballot.
        unsigned long long k = red[par][lane & 7];
        k = dpp_u64max_step<ROW_SHR1>(k);
        k = dpp_u64max_step<ROW_SHR2>(k);
        k = dpp_u64max_step<ROW_SHR4>(k);
        unsigned blo = (unsigned)__builtin_amdgcn_readlane(
            (int)(unsigned)(k & 0xffffffffu), 7);
        int wiu = (int)(~blo);  // uniform (SGPR) winner index
        cx = xLds[wiu];  // 3 independent broadcast ds_read_b32
        cy = yLds[wiu];
        cz = zLds[wiu];
        if (tid == 0) ctrLds[s] = make_float4(cx, cy, cz, 0.0f);
    }

    // --- single coalesced write-out of all centers
    __syncthreads();
    for (int s = tid; s < SS; s += 512) {
        float4 c = ctrLds[s];
        o0[s] = c.x;
        o0[SS + s] = c.y;
        o0[2 * SS + s] = c.z;
        ctr[s] = c;
    }
}

// ---------------------------------------------------------------------------
// Fused ball-query + MLP + maxpool. Block = 128 threads (2 waves), 2 centers.
// LDS halved (R9): h2 reuses h1's buffer in place -> ~17KB -> ~9 blocks/CU.
// ---------------------------------------------------------------------------
__global__ __launch_bounds__(128) void bqmlp_kernel(const float* __restrict__ xyz_all,
                                                    const float4* __restrict__ wsCtr,
                                                    const float* __restrict__ w1T,
                                                    const float* __restrict__ b1,
                                                    const float* __restrict__ w2T,
                                                    const float* __restrict__ b2,
                                                    const float* __restrict__ w3T,
                                                    const float* __restrict__ b3,
                                                    float* __restrict__ out1) {
    const int b = blockIdx.x >> 10;            // 1024 blocks per batch
    const int s0 = (blockIdx.x & 1023) * 2;    // 2 centers per block
    const float* xyz = xyz_all + (size_t)b * NN * 3;

    __shared__ float relF[2 * KNB * 3];  // [64 rows][3]
    __shared__ float hT[64 * 64];        // [ch][row] — holds h1, then h2

    const int tid = threadIdx.x;
    const int cb = __builtin_amdgcn_readfirstlane(tid >> 6);  // wave id (uniform)
    const int l = tid & 63;

    // ---- ball query: wave cb handles center s0+cb
    {
        float4 cc = wsCtr[(size_t)b * SS + s0 + cb];
        float ccx = cc.x, ccy = cc.y, ccz = cc.z;
        const float R2 = (float)(0.2 * 0.2);
        int total = 0;
        float fx = 0.f, fy = 0.f, fz = 0.f;
        bool have = false;
        for (int chunk = 0; chunk < 128 && total < KNB; ++chunk) {
            int p = chunk * 64 + l;
            float x = xyz[p * 3 + 0], y = xyz[p * 3 + 1], z = xyz[p * 3 + 2];
            float d = sqdist_exact(ccx, ccy, ccz, x, y, z);
            bool hit = (d <= R2);
            unsigned long long mask = __ballot(hit);
            int cnt = __popcll(mask);
            if (cnt) {
                int pos = total + __popcll(mask & ((1ull << l) - 1ull));
                float rx = x - ccx, ry = y - ccy, rz = z - ccz;  // single subs: exact
                if (hit && pos < KNB) {
                    relF[(cb * KNB + pos) * 3 + 0] = rx;
                    relF[(cb * KNB + pos) * 3 + 1] = ry;
                    relF[(cb * KNB + pos) * 3 + 2] = rz;
                }
                if (hit && pos == 0) { fx = rx; fy = ry; fz = rz; have = true; }
                total += cnt;
            }
        }
        unsigned long long hm = __ballot(have);
        if (total < KNB) {
            int src = __ffsll((long long)hm) - 1;
            float gx = __shfl(fx, src), gy = __shfl(fy, src), gz = __shfl(fz, src);
            if (l >= total && l < KNB) {
                relF[(cb * KNB + l) * 3 + 0] = gx;
                relF[(cb * KNB + l) * 3 + 1] = gy;
                relF[(cb * KNB + l) * 3 + 2] = gz;
            }
        }
    }
    __syncthreads();

    const int r = l;  // row 0..63: rows 0..31 center s0, rows 32..63 center s0+1

    // ---- layer 1: rel(3) -> 64, thread covers ch block cb*32..+31 for row r
    {
        float rx = relF[r * 3 + 0], ry = relF[r * 3 + 1], rz = relF[r * 3 + 2];
#pragma unroll
        for (int i = 0; i < 32; ++i) {
            int ch = cb * 32 + i;
            float h = b1[ch];
            h = fmaf(rx, w1T[0 * 64 + ch], h);
            h = fmaf(ry, w1T[1 * 64 + ch], h);
            h = fmaf(rz, w1T[2 * 64 + ch], h);
            hT[ch * 64 + r] = fmaxf(h, 0.0f);
        }
    }
    __syncthreads();

    // ---- layer 2: 64 -> 64 (reads h1 from hT; after barrier, h2 overwrites)
    {
        float acc[32];
#pragma unroll
        for (int i = 0; i < 32; ++i) acc[i] = b2[cb * 32 + i];
#pragma unroll 4
        for (int j = 0; j < 64; ++j) {
            float a = hT[j * 64 + r];
            const float* wrow = w2T + j * 64 + cb * 32;
#pragma unroll
            for (int i = 0; i < 32; ++i) acc[i] = fmaf(a, wrow[i], acc[i]);
        }
        __syncthreads();  // all h1 reads complete before overwrite
#pragma unroll
        for (int i = 0; i < 32; ++i) hT[(cb * 32 + i) * 64 + r] = fmaxf(acc[i], 0.0f);
    }
    __syncthreads();

    // ---- layer 3: 64 -> 128, fused relu + maxpool over the 32 rows/center
    {
        float acc[64];
#pragma unroll
        for (int i = 0; i < 64; ++i) acc[i] = b3[cb * 64 + i];
#pragma unroll 2
        for (int j = 0; j < 64; ++j) {
            float a = hT[j * 64 + r];
            const float* wrow = w3T + j * 128 + cb * 64;
#pragma unroll
            for (int i = 0; i < 64; ++i) acc[i] = fmaf(a, wrow[i], acc[i]);
        }
#pragma unroll
        for (int i = 0; i < 64; ++i) {
            float v = fmaxf(acc[i], 0.0f);
            v = fmaxf(v, __shfl_xor(v, 1));
            v = fmaxf(v, __shfl_xor(v, 2));
            v = fmaxf(v, __shfl_xor(v, 4));
            v = fmaxf(v, __shfl_xor(v, 8));
            v = fmaxf(v, __shfl_xor(v, 16));
            acc[i] = v;
        }
        if ((l & 31) == 0) {
            int sA = s0 + (l >> 5);
            float* op = out1 + ((size_t)b * 128 + cb * 64) * SS + sA;
#pragma unroll
            for (int i = 0; i < 64; ++i) op[(size_t)i * SS] = acc[i];
        }
    }
}

extern "C" void kernel_launch(void* const* d_in, const int* in_sizes, int n_in,
                              void* d_out, int out_size, void* d_ws, size_t ws_size,
                              hipStream_t stream) {
    (void)in_sizes; (void)n_in; (void)out_size; (void)ws_size;
    const float* xyz = (const float*)d_in[0];
    // d_in[1] = features : unused by the reference
    const float* w1 = (const float*)d_in[2];
    const float* b1 = (const float*)d_in[3];
    const float* w2 = (const float*)d_in[4];
    const float* b2 = (const float*)d_in[5];
    const float* w3 = (const float*)d_in[6];
    const float* b3 = (const float*)d_in[7];
    float* out = (float*)d_out;

    // workspace layout
    float4* wsCtr = (float4*)d_ws;              // B*S float4      (256 KB)
    float4* wsSorted = wsCtr + BB * SS;         // B*N float4      (1 MB)
    float* w1T = (float*)(wsSorted + BB * NN);  // 192 f
    float* w2T = w1T + 192;                     // 4096 f
    float* w3T = w2T + 4096;                    // 8192 f

    prep_kernel<<<1, 256, 0, stream>>>(w1, w2, w3, w1T, w2T, w3T);
    fps_kernel<<<BB, 512, 0, stream>>>(xyz, wsSorted, wsCtr, out);
    bqmlp_kernel<<<BB * (SS / 2), 128, 0, stream>>>(xyz, wsCtr, w1T, b1, w2T, b2,
                                                    w3T, b3, out + BB * 3 * SS);
}